// Round 1
// baseline (7762.519 us; speedup 1.0000x reference)
//
#include <hip/hip_runtime.h>
#include <math.h>

// ---------------------------------------------------------------------------
// GCN 2-layer forward: h1 = relu(Ahat (X W1) + b1); logits = Ahat (h1 W2) + b2
// out = [logits (N*16), log_softmax (N*16)]
// Ahat = D^-1/2 (A + I) D^-1/2 with in-degree (over dst) incl. self loops.
// ---------------------------------------------------------------------------

__global__ void k_zero_deg(int* __restrict__ deg, int n) {
    int i = blockIdx.x * blockDim.x + threadIdx.x;
    if (i < n) deg[i] = 0;
}

__global__ void k_count(const int* __restrict__ dst, int E, int* __restrict__ deg) {
    int e = blockIdx.x * blockDim.x + threadIdx.x;
    if (e < E) atomicAdd(&deg[dst[e]], 1);
}

__global__ void k_dinv(const int* __restrict__ deg, float* __restrict__ dinv, int n) {
    int i = blockIdx.x * blockDim.x + threadIdx.x;
    if (i < n) dinv[i] = rsqrtf((float)(deg[i] + 1));  // +1 self loop; always > 0
}

// h = x @ W1 : [n,128] x [128,128]. 256 thr/block, 16 rows/block.
// thread: 4 rows (rg + 4j) x 2 cols (c, c+64).
__global__ void k_gemm1(const float* __restrict__ x, const float* __restrict__ W,
                        float* __restrict__ h, int n) {
    __shared__ float xs[16][128];
    const int t = threadIdx.x;
    const int row0 = blockIdx.x * 16;
    for (int i = t; i < 512; i += 256) {          // 512 float4 = 16x128 floats
        int r = i >> 5, kc = (i & 31) << 2;
        int gr = row0 + r;
        float4 v = make_float4(0.f, 0.f, 0.f, 0.f);
        if (gr < n) v = *(const float4*)(x + (size_t)gr * 128 + kc);
        *(float4*)(&xs[r][kc]) = v;
    }
    __syncthreads();
    const int c = t & 63;   // cols c and c+64
    const int rg = t >> 6;  // rows rg, rg+4, rg+8, rg+12 (wave-uniform -> LDS broadcast)
    float acc[4][2] = {};
    for (int k = 0; k < 128; k += 4) {
        float4 xv[4];
#pragma unroll
        for (int j = 0; j < 4; ++j) xv[j] = *(const float4*)(&xs[rg + 4 * j][k]);
#pragma unroll
        for (int kk = 0; kk < 4; ++kk) {
            float w0 = W[(k + kk) * 128 + c];
            float w1 = W[(k + kk) * 128 + c + 64];
#pragma unroll
            for (int j = 0; j < 4; ++j) {
                float xk = (&xv[j].x)[kk];
                acc[j][0] = fmaf(xk, w0, acc[j][0]);
                acc[j][1] = fmaf(xk, w1, acc[j][1]);
            }
        }
    }
#pragma unroll
    for (int j = 0; j < 4; ++j) {
        int gr = row0 + rg + 4 * j;
        if (gr < n) {
            h[(size_t)gr * 128 + c] = acc[j][0];
            h[(size_t)gr * 128 + c + 64] = acc[j][1];
        }
    }
}

// a1[i][:] = dinv[i]^2 * h[i][:] + b1[:]   (self-loop term + bias)
__global__ void k_init_a1(const float* __restrict__ h, const float* __restrict__ dinv,
                          const float* __restrict__ b1, float* __restrict__ a1, int n) {
    int idx = blockIdx.x * blockDim.x + threadIdx.x;  // n*32 threads
    if (idx < n * 32) {
        int node = idx >> 5;
        int c4 = (idx & 31) << 2;
        float s = dinv[node];
        s = s * s;
        float4 hv = *(const float4*)(h + (size_t)node * 128 + c4);
        float4 bv = *(const float4*)(b1 + c4);
        float4 o;
        o.x = fmaf(hv.x, s, bv.x);
        o.y = fmaf(hv.y, s, bv.y);
        o.z = fmaf(hv.z, s, bv.z);
        o.w = fmaf(hv.w, s, bv.w);
        *(float4*)(a1 + (size_t)node * 128 + c4) = o;
    }
}

// edge-parallel scatter: 32 threads per edge, float4 gather + 4 atomics
__global__ void k_scatter1(const int* __restrict__ src, const int* __restrict__ dst,
                           const float* __restrict__ h, const float* __restrict__ dinv,
                           float* __restrict__ a1, int E) {
    int tid = blockIdx.x * blockDim.x + threadIdx.x;
    int e = tid >> 5;
    if (e >= E) return;
    int lane = tid & 31;
    int s = src[e], d = dst[e];
    float w = dinv[s] * dinv[d];
    float4 hv = *(const float4*)(h + (size_t)s * 128 + (lane << 2));
    float* base = a1 + (size_t)d * 128 + (lane << 2);
    atomicAdd(base + 0, hv.x * w);
    atomicAdd(base + 1, hv.y * w);
    atomicAdd(base + 2, hv.z * w);
    atomicAdd(base + 3, hv.w * w);
}

// h2 = relu(a1) @ W2 : [n,128] x [128,16]. 256 thr/block, 32 rows/block.
__global__ void k_gemm2(const float* __restrict__ a1, const float* __restrict__ W2,
                        float* __restrict__ h2, int n) {
    __shared__ float as[32][132];   // +4 pad: conflict-free
    __shared__ float wst[16][132];  // W2 transposed: wst[c][k] = W2[k*16+c]
    const int t = threadIdx.x;
    const int row0 = blockIdx.x * 32;
    for (int i = t; i < 2048; i += 256) {
        int k = i >> 4, c = i & 15;
        wst[c][k] = W2[i];
    }
    for (int i = t; i < 1024; i += 256) {  // 1024 float4 = 32x128 floats
        int r = i >> 5, kc = (i & 31) << 2;
        int gr = row0 + r;
        float4 v = make_float4(0.f, 0.f, 0.f, 0.f);
        if (gr < n) v = *(const float4*)(a1 + (size_t)gr * 128 + kc);
        v.x = fmaxf(v.x, 0.f); v.y = fmaxf(v.y, 0.f);
        v.z = fmaxf(v.z, 0.f); v.w = fmaxf(v.w, 0.f);
        *(float4*)(&as[r][kc]) = v;
    }
    __syncthreads();
    const int c = t & 15, lr = t >> 4;  // rows lr and lr+16
    float acc0 = 0.f, acc1 = 0.f;
    for (int k = 0; k < 128; k += 4) {
        float4 wv = *(const float4*)(&wst[c][k]);
        float4 a0 = *(const float4*)(&as[lr][k]);
        float4 b0 = *(const float4*)(&as[lr + 16][k]);
        acc0 = fmaf(a0.x, wv.x, fmaf(a0.y, wv.y, fmaf(a0.z, wv.z, fmaf(a0.w, wv.w, acc0))));
        acc1 = fmaf(b0.x, wv.x, fmaf(b0.y, wv.y, fmaf(b0.z, wv.z, fmaf(b0.w, wv.w, acc1))));
    }
    int g0 = row0 + lr, g1 = row0 + lr + 16;
    if (g0 < n) h2[(size_t)g0 * 16 + c] = acc0;
    if (g1 < n) h2[(size_t)g1 * 16 + c] = acc1;
}

// out[i][:] = dinv[i]^2 * h2[i][:] + b2[:]
__global__ void k_init_out(const float* __restrict__ h2, const float* __restrict__ dinv,
                           const float* __restrict__ b2, float* __restrict__ out, int n) {
    int idx = blockIdx.x * blockDim.x + threadIdx.x;  // n*4 threads
    if (idx < n * 4) {
        int node = idx >> 2;
        int c4 = (idx & 3) << 2;
        float s = dinv[node];
        s = s * s;
        float4 hv = *(const float4*)(h2 + (size_t)node * 16 + c4);
        float4 bv = *(const float4*)(b2 + c4);
        float4 o;
        o.x = fmaf(hv.x, s, bv.x);
        o.y = fmaf(hv.y, s, bv.y);
        o.z = fmaf(hv.z, s, bv.z);
        o.w = fmaf(hv.w, s, bv.w);
        *(float4*)(out + (size_t)node * 16 + c4) = o;
    }
}

// edge-parallel scatter layer 2: 4 threads per edge
__global__ void k_scatter2(const int* __restrict__ src, const int* __restrict__ dst,
                           const float* __restrict__ h2, const float* __restrict__ dinv,
                           float* __restrict__ out, int E) {
    int tid = blockIdx.x * blockDim.x + threadIdx.x;
    int e = tid >> 2;
    if (e >= E) return;
    int lane = tid & 3;
    int s = src[e], d = dst[e];
    float w = dinv[s] * dinv[d];
    float4 hv = *(const float4*)(h2 + (size_t)s * 16 + (lane << 2));
    float* base = out + (size_t)d * 16 + (lane << 2);
    atomicAdd(base + 0, hv.x * w);
    atomicAdd(base + 1, hv.y * w);
    atomicAdd(base + 2, hv.z * w);
    atomicAdd(base + 3, hv.w * w);
}

// second output: log_softmax over C=16, one thread per node
__global__ void k_logsoftmax(float* __restrict__ out, int n) {
    int node = blockIdx.x * blockDim.x + threadIdx.x;
    if (node >= n) return;
    float v[16];
#pragma unroll
    for (int j = 0; j < 4; ++j) {
        float4 t = *(const float4*)(out + (size_t)node * 16 + j * 4);
        v[j * 4 + 0] = t.x; v[j * 4 + 1] = t.y; v[j * 4 + 2] = t.z; v[j * 4 + 3] = t.w;
    }
    float m = v[0];
#pragma unroll
    for (int j = 1; j < 16; ++j) m = fmaxf(m, v[j]);
    float ssum = 0.f;
#pragma unroll
    for (int j = 0; j < 16; ++j) ssum += expf(v[j] - m);
    float ls = m + logf(ssum);
    float* o2 = out + (size_t)n * 16 + (size_t)node * 16;
#pragma unroll
    for (int j = 0; j < 4; ++j) {
        float4 t;
        t.x = v[j * 4 + 0] - ls; t.y = v[j * 4 + 1] - ls;
        t.z = v[j * 4 + 2] - ls; t.w = v[j * 4 + 3] - ls;
        *(float4*)(o2 + j * 4) = t;
    }
}

extern "C" void kernel_launch(void* const* d_in, const int* in_sizes, int n_in,
                              void* d_out, int out_size, void* d_ws, size_t ws_size,
                              hipStream_t stream) {
    const float* x  = (const float*)d_in[0];
    const int*   ei = (const int*)d_in[1];
    const float* W1 = (const float*)d_in[2];
    const float* b1 = (const float*)d_in[3];
    const float* W2 = (const float*)d_in[4];
    const float* b2 = (const float*)d_in[5];
    float* out = (float*)d_out;

    const int n = in_sizes[0] / 128;   // 100000
    const int E = in_sizes[1] / 2;     // 1600000
    const int* src = ei;
    const int* dst = ei + E;

    int*   deg  = (int*)d_ws;                        // n ints
    float* dinv = (float*)d_ws + n;                  // n floats
    float* h    = (float*)d_ws + 2 * (size_t)n;      // n*128 floats
    float* a1   = h + (size_t)n * 128;               // n*128 floats
    float* h2   = h;                                 // reuse h after a1 built (n*16)

    k_zero_deg<<<(n + 255) / 256, 256, 0, stream>>>(deg, n);
    k_count<<<(E + 255) / 256, 256, 0, stream>>>(dst, E, deg);
    k_dinv<<<(n + 255) / 256, 256, 0, stream>>>(deg, dinv, n);

    k_gemm1<<<(n + 15) / 16, 256, 0, stream>>>(x, W1, h, n);
    k_init_a1<<<(n * 32 + 255) / 256, 256, 0, stream>>>(h, dinv, b1, a1, n);
    k_scatter1<<<(int)(((size_t)E * 32 + 255) / 256), 256, 0, stream>>>(src, dst, h, dinv, a1, E);

    k_gemm2<<<(n + 31) / 32, 256, 0, stream>>>(a1, W2, h2, n);
    k_init_out<<<(n * 4 + 255) / 256, 256, 0, stream>>>(h2, dinv, b2, out, n);
    k_scatter2<<<(int)(((size_t)E * 4 + 255) / 256), 256, 0, stream>>>(src, dst, h2, dinv, out, E);

    k_logsoftmax<<<(n + 255) / 256, 256, 0, stream>>>(out, n);
}

// Round 2
// 639.315 us; speedup vs baseline: 12.1419x; 12.1419x over previous
//
#include <hip/hip_runtime.h>
#include <math.h>

// ---------------------------------------------------------------------------
// GCN 2-layer forward, CSR-gather formulation (no float atomics):
//   deg -> rowptr (scan) -> col fill
//   h   = (x @ W1)            [bf16, n x 128]
//   a1  = relu(Ahat h + b1)   [f32,  n x 128]   (gather, self+bias+relu fused)
//   h2  = a1 @ W2             [f32,  n x 16]
//   out = [Ahat h2 + b2 ; log_softmax(...)]     (gather, softmax fused)
// ---------------------------------------------------------------------------

#define SCAN_CHUNK 1024  // elements per scan block (256 thr x 4)

__device__ __forceinline__ float bf2f(unsigned short u) {
    return __uint_as_float(((unsigned int)u) << 16);
}
__device__ __forceinline__ unsigned short f2bf(float f) {
    unsigned int u = __float_as_uint(f);
    unsigned int r = (u + 0x7fffu + ((u >> 16) & 1u)) >> 16;  // RNE
    return (unsigned short)r;
}

__global__ void k_zero_deg(int* __restrict__ deg, int n) {
    int i = blockIdx.x * blockDim.x + threadIdx.x;
    if (i < n) deg[i] = 0;
}

__global__ void k_count(const int* __restrict__ dst, int E, int* __restrict__ deg) {
    int e = blockIdx.x * blockDim.x + threadIdx.x;
    if (e < E) atomicAdd(&deg[dst[e]], 1);
}

__global__ void k_dinv(const int* __restrict__ deg, float* __restrict__ dinv, int n) {
    int i = blockIdx.x * blockDim.x + threadIdx.x;
    if (i < n) dinv[i] = rsqrtf((float)(deg[i] + 1));  // +1 self loop
}

// ---- exclusive scan of deg[n] -> rowptr[n+1] (3-kernel hierarchical) ----
__global__ void k_scan_a(const int* __restrict__ deg, int* __restrict__ bsum, int n) {
    __shared__ int sh[256];
    const int t = threadIdx.x, b = blockIdx.x;
    const int base = b * SCAN_CHUNK + t * 4;
    int s4 = 0;
#pragma unroll
    for (int q = 0; q < 4; ++q)
        if (base + q < n) s4 += deg[base + q];
    sh[t] = s4;
    __syncthreads();
    for (int o = 1; o < 256; o <<= 1) {
        int x = 0;
        if (t >= o) x = sh[t - o];
        __syncthreads();
        if (t >= o) sh[t] += x;
        __syncthreads();
    }
    if (t == 255) bsum[b] = sh[255];
}

__global__ void k_scan_b(int* __restrict__ bsum, int* __restrict__ rowptr, int nblk, int n) {
    if (threadIdx.x == 0) {
        int run = 0;
        for (int b = 0; b < nblk; ++b) {
            int v = bsum[b];
            bsum[b] = run;
            run += v;
        }
        rowptr[n] = run;  // == E
    }
}

__global__ void k_scan_c(const int* __restrict__ deg, const int* __restrict__ bsum,
                         int* __restrict__ rowptr, int* __restrict__ pos, int n) {
    __shared__ int sh[256];
    const int t = threadIdx.x, b = blockIdx.x;
    const int base = b * SCAN_CHUNK + t * 4;
    int d[4];
    int s4 = 0;
#pragma unroll
    for (int q = 0; q < 4; ++q) {
        d[q] = (base + q < n) ? deg[base + q] : 0;   // read BEFORE pos write (alias)
        s4 += d[q];
    }
    sh[t] = s4;
    __syncthreads();
    for (int o = 1; o < 256; o <<= 1) {
        int x = 0;
        if (t >= o) x = sh[t - o];
        __syncthreads();
        if (t >= o) sh[t] += x;
        __syncthreads();
    }
    int off = sh[t] - s4 + bsum[b];  // exclusive prefix
#pragma unroll
    for (int q = 0; q < 4; ++q) {
        if (base + q < n) {
            rowptr[base + q] = off;
            pos[base + q] = off;
            off += d[q];
        }
    }
}

__global__ void k_fill(const int* __restrict__ src, const int* __restrict__ dst, int E,
                       int* __restrict__ pos, int* __restrict__ col) {
    int e = blockIdx.x * blockDim.x + threadIdx.x;
    if (e < E) {
        int p = atomicAdd(&pos[dst[e]], 1);
        col[p] = src[e];
    }
}

// ---- gemm1: h(bf16) = x @ W1, [n,128]x[128,128]. 32 rows/block, 256 thr ----
// thread: rows rg+8j (j=0..3), cols c+32i (i=0..3)
__global__ void k_gemm1(const float* __restrict__ x, const float* __restrict__ W,
                        unsigned short* __restrict__ h, int n) {
    __shared__ float xs[32][128];  // 16 KB
    __shared__ float ws[64][128];  // 32 KB, one K-half of W at a time
    const int t = threadIdx.x;
    const int row0 = blockIdx.x * 32;
    // stage x rows (float4 coalesced)
    for (int j = 0; j < 4; ++j) {
        int idx = t + 256 * j;            // 0..1023 float4s
        int r = idx >> 5, c4 = (idx & 31) << 2;
        int gr = row0 + r;
        float4 v = make_float4(0.f, 0.f, 0.f, 0.f);
        if (gr < n) v = *(const float4*)(x + (size_t)gr * 128 + c4);
        *(float4*)(&xs[r][c4]) = v;
    }
    const int c = t & 31;         // cols c, c+32, c+64, c+96
    const int rg = t >> 5;        // rows rg, rg+8, rg+16, rg+24
    float acc[4][4] = {};
    for (int half = 0; half < 2; ++half) {
        __syncthreads();  // waves done with previous ws (and xs staged on iter 0)
        for (int j = 0; j < 8; ++j) {
            int idx = t + 256 * j;        // 0..2047 float4s = 64x128 floats
            int kl = idx >> 5, c4 = (idx & 31) << 2;
            *(float4*)(&ws[kl][c4]) = *(const float4*)(W + (size_t)(half * 64 + kl) * 128 + c4);
        }
        __syncthreads();
        for (int k = 0; k < 64; k += 4) {
            float4 xv[4];
#pragma unroll
            for (int j = 0; j < 4; ++j)
                xv[j] = *(const float4*)(&xs[rg + 8 * j][half * 64 + k]);
#pragma unroll
            for (int kk = 0; kk < 4; ++kk) {
                float w0 = ws[k + kk][c];
                float w1 = ws[k + kk][c + 32];
                float w2 = ws[k + kk][c + 64];
                float w3 = ws[k + kk][c + 96];
#pragma unroll
                for (int j = 0; j < 4; ++j) {
                    float xk = (&xv[j].x)[kk];
                    acc[j][0] = fmaf(xk, w0, acc[j][0]);
                    acc[j][1] = fmaf(xk, w1, acc[j][1]);
                    acc[j][2] = fmaf(xk, w2, acc[j][2]);
                    acc[j][3] = fmaf(xk, w3, acc[j][3]);
                }
            }
        }
    }
#pragma unroll
    for (int j = 0; j < 4; ++j) {
        int gr = row0 + rg + 8 * j;
        if (gr < n) {
#pragma unroll
            for (int i = 0; i < 4; ++i)
                h[(size_t)gr * 128 + c + 32 * i] = f2bf(acc[j][i]);
        }
    }
}

// ---- gather1: a1 = relu(Ahat h + b1). 32 lanes per node (float4 of features) ----
__global__ void k_gather1(const unsigned short* __restrict__ h, const int* __restrict__ rowptr,
                          const int* __restrict__ col, const float* __restrict__ dinv,
                          const float* __restrict__ b1, float* __restrict__ a1, int n) {
    const int t = threadIdx.x;
    const int d = blockIdx.x * 8 + (t >> 5);
    if (d >= n) return;
    const int lane = t & 31;
    const float dd = dinv[d];
    // self loop: weight dd*dd, plus bias
    float4 acc;
    {
        ushort4 u = *(const ushort4*)(h + (size_t)d * 128 + lane * 4);
        float w = dd * dd;
        float4 bv = *(const float4*)(b1 + lane * 4);
        acc.x = fmaf(bf2f(u.x), w, bv.x);
        acc.y = fmaf(bf2f(u.y), w, bv.y);
        acc.z = fmaf(bf2f(u.z), w, bv.z);
        acc.w = fmaf(bf2f(u.w), w, bv.w);
    }
    float4 acc2 = make_float4(0.f, 0.f, 0.f, 0.f);
    int k = rowptr[d];
    const int end = rowptr[d + 1];
    for (; k + 1 < end; k += 2) {
        int s0 = col[k], s1 = col[k + 1];
        float w0 = dinv[s0] * dd, w1 = dinv[s1] * dd;
        ushort4 u0 = *(const ushort4*)(h + (size_t)s0 * 128 + lane * 4);
        ushort4 u1 = *(const ushort4*)(h + (size_t)s1 * 128 + lane * 4);
        acc.x = fmaf(bf2f(u0.x), w0, acc.x);
        acc.y = fmaf(bf2f(u0.y), w0, acc.y);
        acc.z = fmaf(bf2f(u0.z), w0, acc.z);
        acc.w = fmaf(bf2f(u0.w), w0, acc.w);
        acc2.x = fmaf(bf2f(u1.x), w1, acc2.x);
        acc2.y = fmaf(bf2f(u1.y), w1, acc2.y);
        acc2.z = fmaf(bf2f(u1.z), w1, acc2.z);
        acc2.w = fmaf(bf2f(u1.w), w1, acc2.w);
    }
    if (k < end) {
        int s0 = col[k];
        float w0 = dinv[s0] * dd;
        ushort4 u0 = *(const ushort4*)(h + (size_t)s0 * 128 + lane * 4);
        acc.x = fmaf(bf2f(u0.x), w0, acc.x);
        acc.y = fmaf(bf2f(u0.y), w0, acc.y);
        acc.z = fmaf(bf2f(u0.z), w0, acc.z);
        acc.w = fmaf(bf2f(u0.w), w0, acc.w);
    }
    float4 o;
    o.x = fmaxf(acc.x + acc2.x, 0.f);
    o.y = fmaxf(acc.y + acc2.y, 0.f);
    o.z = fmaxf(acc.z + acc2.z, 0.f);
    o.w = fmaxf(acc.w + acc2.w, 0.f);
    *(float4*)(a1 + (size_t)d * 128 + lane * 4) = o;
}

// ---- gemm2: h2 = a1 @ W2 : [n,128]x[128,16]. 32 rows/block ----
__global__ void k_gemm2(const float* __restrict__ a1, const float* __restrict__ W2,
                        float* __restrict__ h2, int n) {
    __shared__ float as[32][132];
    __shared__ float wst[16][132];  // W2 transposed
    const int t = threadIdx.x;
    const int row0 = blockIdx.x * 32;
    for (int i = t; i < 2048; i += 256) {
        int k = i >> 4, c = i & 15;
        wst[c][k] = W2[i];
    }
    for (int i = t; i < 1024; i += 256) {
        int r = i >> 5, kc = (i & 31) << 2;
        int gr = row0 + r;
        float4 v = make_float4(0.f, 0.f, 0.f, 0.f);
        if (gr < n) v = *(const float4*)(a1 + (size_t)gr * 128 + kc);
        *(float4*)(&as[r][kc]) = v;
    }
    __syncthreads();
    const int c = t & 15, lr = t >> 4;
    float acc0 = 0.f, acc1 = 0.f;
    for (int k = 0; k < 128; k += 4) {
        float4 wv = *(const float4*)(&wst[c][k]);
        float4 a0 = *(const float4*)(&as[lr][k]);
        float4 b0 = *(const float4*)(&as[lr + 16][k]);
        acc0 = fmaf(a0.x, wv.x, fmaf(a0.y, wv.y, fmaf(a0.z, wv.z, fmaf(a0.w, wv.w, acc0))));
        acc1 = fmaf(b0.x, wv.x, fmaf(b0.y, wv.y, fmaf(b0.z, wv.z, fmaf(b0.w, wv.w, acc1))));
    }
    int g0 = row0 + lr, g1 = row0 + lr + 16;
    if (g0 < n) h2[(size_t)g0 * 16 + c] = acc0;
    if (g1 < n) h2[(size_t)g1 * 16 + c] = acc1;
}

// ---- gather2: logits = Ahat h2 + b2, then log_softmax. 4 lanes per node ----
__global__ void k_gather2(const float* __restrict__ h2, const int* __restrict__ rowptr,
                          const int* __restrict__ col, const float* __restrict__ dinv,
                          const float* __restrict__ b2, float* __restrict__ out, int n) {
    const int t = threadIdx.x;
    const int d = blockIdx.x * 64 + (t >> 2);
    if (d >= n) return;
    const int l = t & 3;
    const float dd = dinv[d];
    float4 acc, acc2 = make_float4(0.f, 0.f, 0.f, 0.f);
    {
        float w = dd * dd;
        float4 hv = *(const float4*)(h2 + (size_t)d * 16 + l * 4);
        float4 bv = *(const float4*)(b2 + l * 4);
        acc.x = fmaf(hv.x, w, bv.x);
        acc.y = fmaf(hv.y, w, bv.y);
        acc.z = fmaf(hv.z, w, bv.z);
        acc.w = fmaf(hv.w, w, bv.w);
    }
    int k = rowptr[d];
    const int end = rowptr[d + 1];
    for (; k + 1 < end; k += 2) {
        int s0 = col[k], s1 = col[k + 1];
        float w0 = dinv[s0] * dd, w1 = dinv[s1] * dd;
        float4 h0 = *(const float4*)(h2 + (size_t)s0 * 16 + l * 4);
        float4 h1 = *(const float4*)(h2 + (size_t)s1 * 16 + l * 4);
        acc.x = fmaf(h0.x, w0, acc.x);
        acc.y = fmaf(h0.y, w0, acc.y);
        acc.z = fmaf(h0.z, w0, acc.z);
        acc.w = fmaf(h0.w, w0, acc.w);
        acc2.x = fmaf(h1.x, w1, acc2.x);
        acc2.y = fmaf(h1.y, w1, acc2.y);
        acc2.z = fmaf(h1.z, w1, acc2.z);
        acc2.w = fmaf(h1.w, w1, acc2.w);
    }
    if (k < end) {
        int s0 = col[k];
        float w0 = dinv[s0] * dd;
        float4 h0 = *(const float4*)(h2 + (size_t)s0 * 16 + l * 4);
        acc.x = fmaf(h0.x, w0, acc.x);
        acc.y = fmaf(h0.y, w0, acc.y);
        acc.z = fmaf(h0.z, w0, acc.z);
        acc.w = fmaf(h0.w, w0, acc.w);
    }
    acc.x += acc2.x; acc.y += acc2.y; acc.z += acc2.z; acc.w += acc2.w;
    // logits
    *(float4*)(out + (size_t)d * 16 + l * 4) = acc;
    // log_softmax across the 4-lane group (16 values)
    float m = fmaxf(fmaxf(acc.x, acc.y), fmaxf(acc.z, acc.w));
    m = fmaxf(m, __shfl_xor(m, 1));
    m = fmaxf(m, __shfl_xor(m, 2));
    float e = expf(acc.x - m) + expf(acc.y - m) + expf(acc.z - m) + expf(acc.w - m);
    e += __shfl_xor(e, 1);
    e += __shfl_xor(e, 2);
    float ls = m + logf(e);
    float4 o;
    o.x = acc.x - ls; o.y = acc.y - ls; o.z = acc.z - ls; o.w = acc.w - ls;
    *(float4*)(out + (size_t)n * 16 + (size_t)d * 16 + l * 4) = o;
}

extern "C" void kernel_launch(void* const* d_in, const int* in_sizes, int n_in,
                              void* d_out, int out_size, void* d_ws, size_t ws_size,
                              hipStream_t stream) {
    const float* x  = (const float*)d_in[0];
    const int*   ei = (const int*)d_in[1];
    const float* W1 = (const float*)d_in[2];
    const float* b1 = (const float*)d_in[3];
    const float* W2 = (const float*)d_in[4];
    const float* b2 = (const float*)d_in[5];
    float* out = (float*)d_out;

    const int n = in_sizes[0] / 128;   // 100000
    const int E = in_sizes[1] / 2;     // 1600000
    const int* src = ei;
    const int* dst = ei + E;
    const int NBLK = (n + SCAN_CHUNK - 1) / SCAN_CHUNK;

    // workspace layout (bytes), ~85 MB total
    char* base = (char*)d_ws;
    size_t off = 0;
    int* deg = (int*)(base + off); off += (size_t)n * 4;           // aliased with pos
    int* pos = deg;
    float* dinv = (float*)(base + off); off += (size_t)n * 4;
    int* rowptr = (int*)(base + off); off += ((size_t)n + 4) * 4;
    int* bsum = (int*)(base + off); off += 4096;
    int* col = (int*)(base + off); off += (size_t)E * 4;
    unsigned short* h = (unsigned short*)(base + off); off += (size_t)n * 128 * 2;  // bf16
    float* a1 = (float*)(base + off); off += (size_t)n * 128 * 4;
    float* h2 = (float*)h;  // overlay: h dead after gather1

    // degree + dinv + CSR
    k_zero_deg<<<(n + 255) / 256, 256, 0, stream>>>(deg, n);
    k_count<<<(E + 255) / 256, 256, 0, stream>>>(dst, E, deg);
    k_dinv<<<(n + 255) / 256, 256, 0, stream>>>(deg, dinv, n);
    k_scan_a<<<NBLK, 256, 0, stream>>>(deg, bsum, n);
    k_scan_b<<<1, 64, 0, stream>>>(bsum, rowptr, NBLK, n);
    k_scan_c<<<NBLK, 256, 0, stream>>>(deg, bsum, rowptr, pos, n);
    k_fill<<<(E + 255) / 256, 256, 0, stream>>>(src, dst, E, pos, col);

    // layer 1
    k_gemm1<<<(n + 31) / 32, 256, 0, stream>>>(x, W1, h, n);
    k_gather1<<<(n + 7) / 8, 256, 0, stream>>>(h, rowptr, col, dinv, b1, a1, n);

    // layer 2 (+ fused bias/softmax)
    k_gemm2<<<(n + 31) / 32, 256, 0, stream>>>(a1, W2, h2, n);
    k_gather2<<<(n + 63) / 64, 256, 0, stream>>>(h2, rowptr, col, dinv, b2, out, n);
}

// Round 3
// 561.131 us; speedup vs baseline: 13.8337x; 1.1393x over previous
//
#include <hip/hip_runtime.h>
#include <math.h>

// ---------------------------------------------------------------------------
// GCN 2-layer forward, CSR-gather, fused formulation:
//   deg -> rowptr (scan) -> col fill
//   h'  = dinv * (x @ W1)                      [bf16, n x 128]  (k_gemm1)
//   g'  = dinv * (relu(dinv*sum(h') + b1) @ W2) [f32, n x 16]   (k_gather1f, fused matvec)
//   out = [dinv*sum(g') + b2 ; log_softmax]                      (k_gather2)
// dinv folded into features: norm(s,d)=dinv[s]*dinv[d] => scale rows by dinv
// at production, scale the aggregate by dinv[d] at consumption.
// ---------------------------------------------------------------------------

#define SCAN_CHUNK 1024  // elements per scan block (256 thr x 4)

__device__ __forceinline__ float bf2f(unsigned short u) {
    return __uint_as_float(((unsigned int)u) << 16);
}
__device__ __forceinline__ unsigned short f2bf(float f) {
    unsigned int u = __float_as_uint(f);
    unsigned int r = (u + 0x7fffu + ((u >> 16) & 1u)) >> 16;  // RNE
    return (unsigned short)r;
}

__global__ void k_zero_deg(int* __restrict__ deg, int n) {
    int i = blockIdx.x * blockDim.x + threadIdx.x;
    if (i < n) deg[i] = 0;
}

__global__ void k_count(const int* __restrict__ dst, int E, int* __restrict__ deg) {
    int e = blockIdx.x * blockDim.x + threadIdx.x;
    if (e < E) atomicAdd(&deg[dst[e]], 1);
}

__global__ void k_dinv(const int* __restrict__ deg, float* __restrict__ dinv, int n) {
    int i = blockIdx.x * blockDim.x + threadIdx.x;
    if (i < n) dinv[i] = rsqrtf((float)(deg[i] + 1));  // +1 self loop
}

// ---- exclusive scan of deg[n] -> rowptr[n+1] ----
__global__ void k_scan_a(const int* __restrict__ deg, int* __restrict__ bsum, int n) {
    __shared__ int sh[256];
    const int t = threadIdx.x, b = blockIdx.x;
    const int base = b * SCAN_CHUNK + t * 4;
    int s4 = 0;
#pragma unroll
    for (int q = 0; q < 4; ++q)
        if (base + q < n) s4 += deg[base + q];
    sh[t] = s4;
    __syncthreads();
    for (int o = 1; o < 256; o <<= 1) {
        int x = 0;
        if (t >= o) x = sh[t - o];
        __syncthreads();
        if (t >= o) sh[t] += x;
        __syncthreads();
    }
    if (t == 255) bsum[b] = sh[255];
}

__global__ void k_scan_b(int* __restrict__ bsum, int* __restrict__ rowptr, int nblk, int n) {
    if (threadIdx.x == 0) {
        int run = 0;
        for (int b = 0; b < nblk; ++b) {
            int v = bsum[b];
            bsum[b] = run;
            run += v;
        }
        rowptr[n] = run;  // == E
    }
}

__global__ void k_scan_c(const int* __restrict__ deg, const int* __restrict__ bsum,
                         int* __restrict__ rowptr, int* __restrict__ pos, int n) {
    __shared__ int sh[256];
    const int t = threadIdx.x, b = blockIdx.x;
    const int base = b * SCAN_CHUNK + t * 4;
    int d[4];
    int s4 = 0;
#pragma unroll
    for (int q = 0; q < 4; ++q) {
        d[q] = (base + q < n) ? deg[base + q] : 0;  // read BEFORE pos write (alias)
        s4 += d[q];
    }
    sh[t] = s4;
    __syncthreads();
    for (int o = 1; o < 256; o <<= 1) {
        int x = 0;
        if (t >= o) x = sh[t - o];
        __syncthreads();
        if (t >= o) sh[t] += x;
        __syncthreads();
    }
    int off = sh[t] - s4 + bsum[b];  // exclusive prefix
#pragma unroll
    for (int q = 0; q < 4; ++q) {
        if (base + q < n) {
            rowptr[base + q] = off;
            pos[base + q] = off;
            off += d[q];
        }
    }
}

__global__ void k_fill(const int* __restrict__ src, const int* __restrict__ dst, int E,
                       int* __restrict__ pos, int* __restrict__ col) {
    int e = blockIdx.x * blockDim.x + threadIdx.x;
    if (e < E) {
        int p = atomicAdd(&pos[dst[e]], 1);
        col[p] = src[e];
    }
}

// ---- gemm1: h'(bf16) = dinv * (x @ W1), [n,128]x[128,128]. 32 rows/block ----
__global__ void k_gemm1(const float* __restrict__ x, const float* __restrict__ W,
                        const float* __restrict__ dinv, unsigned short* __restrict__ h,
                        int n) {
    __shared__ float xs[32][128];  // 16 KB
    __shared__ float ws[64][128];  // 32 KB, one K-half of W at a time
    const int t = threadIdx.x;
    const int row0 = blockIdx.x * 32;
    for (int j = 0; j < 4; ++j) {
        int idx = t + 256 * j;
        int r = idx >> 5, c4 = (idx & 31) << 2;
        int gr = row0 + r;
        float4 v = make_float4(0.f, 0.f, 0.f, 0.f);
        if (gr < n) v = *(const float4*)(x + (size_t)gr * 128 + c4);
        *(float4*)(&xs[r][c4]) = v;
    }
    const int c = t & 31;   // cols c, c+32, c+64, c+96
    const int rg = t >> 5;  // rows rg, rg+8, rg+16, rg+24
    float acc[4][4] = {};
    for (int half = 0; half < 2; ++half) {
        __syncthreads();
        for (int j = 0; j < 8; ++j) {
            int idx = t + 256 * j;
            int kl = idx >> 5, c4 = (idx & 31) << 2;
            *(float4*)(&ws[kl][c4]) = *(const float4*)(W + (size_t)(half * 64 + kl) * 128 + c4);
        }
        __syncthreads();
        for (int k = 0; k < 64; k += 4) {
            float4 xv[4];
#pragma unroll
            for (int j = 0; j < 4; ++j)
                xv[j] = *(const float4*)(&xs[rg + 8 * j][half * 64 + k]);
#pragma unroll
            for (int kk = 0; kk < 4; ++kk) {
                float w0 = ws[k + kk][c];
                float w1 = ws[k + kk][c + 32];
                float w2 = ws[k + kk][c + 64];
                float w3 = ws[k + kk][c + 96];
#pragma unroll
                for (int j = 0; j < 4; ++j) {
                    float xk = (&xv[j].x)[kk];
                    acc[j][0] = fmaf(xk, w0, acc[j][0]);
                    acc[j][1] = fmaf(xk, w1, acc[j][1]);
                    acc[j][2] = fmaf(xk, w2, acc[j][2]);
                    acc[j][3] = fmaf(xk, w3, acc[j][3]);
                }
            }
        }
    }
#pragma unroll
    for (int j = 0; j < 4; ++j) {
        int gr = row0 + rg + 8 * j;
        if (gr < n) {
            float s = dinv[gr];
#pragma unroll
            for (int i = 0; i < 4; ++i)
                h[(size_t)gr * 128 + c + 32 * i] = f2bf(acc[j][i] * s);
        }
    }
}

// ---- fused gather1 + relu + (128->16 matvec) + scale:
//   g'[d] = dinv[d] * ( relu( dinv[d]*(h'[d] + sum_{s in N(d)} h'[s]) + b1 ) @ W2 )
// 32 lanes per node; W2 slice (4 rows x 16 cols) register-resident per lane.
__global__ void k_gather1f(const unsigned short* __restrict__ h, const int* __restrict__ rowptr,
                           const int* __restrict__ col, const float* __restrict__ dinv,
                           const float* __restrict__ b1, const float* __restrict__ W2,
                           float* __restrict__ g, int n) {
    const int t = threadIdx.x;
    const int lane = t & 31;
    // per-lane W2 slice: rows 4*lane .. 4*lane+3, all 16 cols (64 consecutive floats)
    float4 wr[16];
    {
        const float4* w2v = (const float4*)(W2 + lane * 64);
#pragma unroll
        for (int j = 0; j < 16; ++j) wr[j] = w2v[j];
    }
    const float4 b1v = *(const float4*)(b1 + lane * 4);

    const int d = blockIdx.x * 8 + (t >> 5);
    if (d >= n) return;
    const float dd = dinv[d];

    // aggregate: self + neighbors (h' rows are pre-scaled by dinv[src])
    float4 acc, acc2 = make_float4(0.f, 0.f, 0.f, 0.f);
    {
        ushort4 u = *(const ushort4*)(h + (size_t)d * 128 + lane * 4);
        acc.x = bf2f(u.x); acc.y = bf2f(u.y); acc.z = bf2f(u.z); acc.w = bf2f(u.w);
    }
    int k = rowptr[d];
    const int end = rowptr[d + 1];
    for (; k + 1 < end; k += 2) {
        int s0 = col[k], s1 = col[k + 1];
        ushort4 u0 = *(const ushort4*)(h + (size_t)s0 * 128 + lane * 4);
        ushort4 u1 = *(const ushort4*)(h + (size_t)s1 * 128 + lane * 4);
        acc.x += bf2f(u0.x); acc.y += bf2f(u0.y); acc.z += bf2f(u0.z); acc.w += bf2f(u0.w);
        acc2.x += bf2f(u1.x); acc2.y += bf2f(u1.y); acc2.z += bf2f(u1.z); acc2.w += bf2f(u1.w);
    }
    if (k < end) {
        int s0 = col[k];
        ushort4 u0 = *(const ushort4*)(h + (size_t)s0 * 128 + lane * 4);
        acc.x += bf2f(u0.x); acc.y += bf2f(u0.y); acc.z += bf2f(u0.z); acc.w += bf2f(u0.w);
    }
    // y = relu(dd*acc + b1)   (4 features per lane: k = 4*lane .. 4*lane+3)
    float y0 = fmaxf(fmaf(acc.x + acc2.x, dd, b1v.x), 0.f);
    float y1 = fmaxf(fmaf(acc.y + acc2.y, dd, b1v.y), 0.f);
    float y2 = fmaxf(fmaf(acc.z + acc2.z, dd, b1v.z), 0.f);
    float y3 = fmaxf(fmaf(acc.w + acc2.w, dd, b1v.w), 0.f);
    // z[c] = sum_k y[k] * W2[k][c]  — per-lane partials over its 4 k's
    float4 z0 = make_float4(0.f, 0.f, 0.f, 0.f);
    float4 z1 = z0, z2 = z0, z3 = z0;
#pragma unroll
    for (int c4 = 0; c4 < 4; ++c4) {
        float4* z = (c4 == 0) ? &z0 : (c4 == 1) ? &z1 : (c4 == 2) ? &z2 : &z3;
        float4 w0 = wr[0 * 4 + c4], w1 = wr[1 * 4 + c4], w2 = wr[2 * 4 + c4], w3 = wr[3 * 4 + c4];
        z->x = fmaf(y0, w0.x, fmaf(y1, w1.x, fmaf(y2, w2.x, fmaf(y3, w3.x, z->x))));
        z->y = fmaf(y0, w0.y, fmaf(y1, w1.y, fmaf(y2, w2.y, fmaf(y3, w3.y, z->y))));
        z->z = fmaf(y0, w0.z, fmaf(y1, w1.z, fmaf(y2, w2.z, fmaf(y3, w3.z, z->z))));
        z->w = fmaf(y0, w0.w, fmaf(y1, w1.w, fmaf(y2, w2.w, fmaf(y3, w3.w, z->w))));
    }
    // butterfly reduce across 32 lanes (masks stay within the 32-lane group)
#pragma unroll
    for (int m = 1; m < 32; m <<= 1) {
        z0.x += __shfl_xor(z0.x, m); z0.y += __shfl_xor(z0.y, m);
        z0.z += __shfl_xor(z0.z, m); z0.w += __shfl_xor(z0.w, m);
        z1.x += __shfl_xor(z1.x, m); z1.y += __shfl_xor(z1.y, m);
        z1.z += __shfl_xor(z1.z, m); z1.w += __shfl_xor(z1.w, m);
        z2.x += __shfl_xor(z2.x, m); z2.y += __shfl_xor(z2.y, m);
        z2.z += __shfl_xor(z2.z, m); z2.w += __shfl_xor(z2.w, m);
        z3.x += __shfl_xor(z3.x, m); z3.y += __shfl_xor(z3.y, m);
        z3.z += __shfl_xor(z3.z, m); z3.w += __shfl_xor(z3.w, m);
    }
    // g'[d] = dd * z ; lanes 0..3 write float4 each
    if (lane < 4) {
        float4 z = (lane == 0) ? z0 : (lane == 1) ? z1 : (lane == 2) ? z2 : z3;
        z.x *= dd; z.y *= dd; z.z *= dd; z.w *= dd;
        *(float4*)(g + (size_t)d * 16 + lane * 4) = z;
    }
}

// ---- gather2: logits = dinv[d]*(g'[d] + sum g'[s]) + b2, then log_softmax ----
__global__ void k_gather2(const float* __restrict__ g, const int* __restrict__ rowptr,
                          const int* __restrict__ col, const float* __restrict__ dinv,
                          const float* __restrict__ b2, float* __restrict__ out, int n) {
    const int t = threadIdx.x;
    const int d = blockIdx.x * 64 + (t >> 2);
    if (d >= n) return;
    const int l = t & 3;
    const float dd = dinv[d];
    float4 acc = *(const float4*)(g + (size_t)d * 16 + l * 4);  // self
    float4 acc2 = make_float4(0.f, 0.f, 0.f, 0.f);
    int k = rowptr[d];
    const int end = rowptr[d + 1];
    for (; k + 1 < end; k += 2) {
        int s0 = col[k], s1 = col[k + 1];
        float4 h0 = *(const float4*)(g + (size_t)s0 * 16 + l * 4);
        float4 h1 = *(const float4*)(g + (size_t)s1 * 16 + l * 4);
        acc.x += h0.x; acc.y += h0.y; acc.z += h0.z; acc.w += h0.w;
        acc2.x += h1.x; acc2.y += h1.y; acc2.z += h1.z; acc2.w += h1.w;
    }
    if (k < end) {
        int s0 = col[k];
        float4 h0 = *(const float4*)(g + (size_t)s0 * 16 + l * 4);
        acc.x += h0.x; acc.y += h0.y; acc.z += h0.z; acc.w += h0.w;
    }
    float4 bv = *(const float4*)(b2 + l * 4);
    acc.x = fmaf(acc.x + acc2.x, dd, bv.x);
    acc.y = fmaf(acc.y + acc2.y, dd, bv.y);
    acc.z = fmaf(acc.z + acc2.z, dd, bv.z);
    acc.w = fmaf(acc.w + acc2.w, dd, bv.w);
    *(float4*)(out + (size_t)d * 16 + l * 4) = acc;
    // log_softmax across the 4-lane group (16 values)
    float m = fmaxf(fmaxf(acc.x, acc.y), fmaxf(acc.z, acc.w));
    m = fmaxf(m, __shfl_xor(m, 1));
    m = fmaxf(m, __shfl_xor(m, 2));
    float e = expf(acc.x - m) + expf(acc.y - m) + expf(acc.z - m) + expf(acc.w - m);
    e += __shfl_xor(e, 1);
    e += __shfl_xor(e, 2);
    float ls = m + logf(e);
    float4 o;
    o.x = acc.x - ls; o.y = acc.y - ls; o.z = acc.z - ls; o.w = acc.w - ls;
    *(float4*)(out + (size_t)n * 16 + (size_t)d * 16 + l * 4) = o;
}

static inline size_t align256(size_t v) { return (v + 255) & ~(size_t)255; }

extern "C" void kernel_launch(void* const* d_in, const int* in_sizes, int n_in,
                              void* d_out, int out_size, void* d_ws, size_t ws_size,
                              hipStream_t stream) {
    const float* x  = (const float*)d_in[0];
    const int*   ei = (const int*)d_in[1];
    const float* W1 = (const float*)d_in[2];
    const float* b1 = (const float*)d_in[3];
    const float* W2 = (const float*)d_in[4];
    const float* b2 = (const float*)d_in[5];
    float* out = (float*)d_out;

    const int n = in_sizes[0] / 128;   // 100000
    const int E = in_sizes[1] / 2;     // 1600000
    const int* src = ei;
    const int* dst = ei + E;
    const int NBLK = (n + SCAN_CHUNK - 1) / SCAN_CHUNK;

    // workspace layout, 256B-aligned, ~40 MB total
    char* base = (char*)d_ws;
    size_t off = 0;
    int* deg = (int*)(base + off); off = align256(off + (size_t)n * 4);  // aliased with pos
    int* pos = deg;
    float* dinv = (float*)(base + off); off = align256(off + (size_t)n * 4);
    int* rowptr = (int*)(base + off); off = align256(off + ((size_t)n + 1) * 4);
    int* bsum = (int*)(base + off); off = align256(off + 4096);
    int* col = (int*)(base + off); off = align256(off + (size_t)E * 4);
    unsigned short* h = (unsigned short*)(base + off); off = align256(off + (size_t)n * 128 * 2);
    float* g = (float*)(base + off); off = align256(off + (size_t)n * 16 * 4);

    // degree + dinv + CSR
    k_zero_deg<<<(n + 255) / 256, 256, 0, stream>>>(deg, n);
    k_count<<<(E + 255) / 256, 256, 0, stream>>>(dst, E, deg);
    k_dinv<<<(n + 255) / 256, 256, 0, stream>>>(deg, dinv, n);
    k_scan_a<<<NBLK, 256, 0, stream>>>(deg, bsum, n);
    k_scan_b<<<1, 64, 0, stream>>>(bsum, rowptr, NBLK, n);
    k_scan_c<<<NBLK, 256, 0, stream>>>(deg, bsum, rowptr, pos, n);
    k_fill<<<(E + 255) / 256, 256, 0, stream>>>(src, dst, E, pos, col);

    // layer 1 (+ fused relu/matvec/scale)
    k_gemm1<<<(n + 31) / 32, 256, 0, stream>>>(x, W1, dinv, h, n);
    k_gather1f<<<(n + 7) / 8, 256, 0, stream>>>(h, rowptr, col, dinv, b1, W2, g, n);

    // layer 2 aggregation (+ fused bias/softmax)
    k_gather2<<<(n + 63) / 64, 256, 0, stream>>>(g, rowptr, col, dinv, b2, out, n);
}

// Round 4
// 491.572 us; speedup vs baseline: 15.7912x; 1.1415x over previous
//
#include <hip/hip_runtime.h>
#include <math.h>

// ---------------------------------------------------------------------------
// GCN 2-layer forward, padded-CSR gather + MFMA gemm1, fused matvec epilogue.
//   deg -> padded rowptr (rows padded to 8, dummy node n with zero features)
//   h'  = dinv * (x @ W1)   [bf16, (n+1) x 128]   (MFMA)
//   g'  = dinv * (relu(dinv*sum h' + b1) @ W2)  [f32, (n+1) x 16]
//   out = [dinv*sum g' + b2 ; log_softmax]
// ---------------------------------------------------------------------------

#define SCAN_CHUNK 1024

typedef __attribute__((ext_vector_type(8))) short short8;
typedef __attribute__((ext_vector_type(4))) float f32x4;

__device__ __forceinline__ float bf2f(unsigned short u) {
    return __uint_as_float(((unsigned int)u) << 16);
}
__device__ __forceinline__ unsigned short f2bf(float f) {
    unsigned int u = __float_as_uint(f);
    unsigned int r = (u + 0x7fffu + ((u >> 16) & 1u)) >> 16;  // RNE
    return (unsigned short)r;
}

// zero deg; zero dummy rows h[n], g[n]
__global__ void k_init(int* __restrict__ deg, unsigned short* __restrict__ h,
                       float* __restrict__ g, int n) {
    int i = blockIdx.x * blockDim.x + threadIdx.x;
    if (i < n) deg[i] = 0;
    if (blockIdx.x == 0) {
        int t = threadIdx.x;
        if (t < 128) h[(size_t)n * 128 + t] = 0;
        if (t < 16) g[(size_t)n * 16 + t] = 0.f;
    }
}

__global__ void k_count(const int* __restrict__ dst, int E, int* __restrict__ deg) {
    int e = blockIdx.x * blockDim.x + threadIdx.x;
    if (e < E) atomicAdd(&deg[dst[e]], 1);
}

__global__ void k_dinv(const int* __restrict__ deg, float* __restrict__ dinv, int n) {
    int i = blockIdx.x * blockDim.x + threadIdx.x;
    if (i < n) dinv[i] = rsqrtf((float)(deg[i] + 1));
}

// ---- exclusive scan of PADDED deg -> rowptr (rows rounded up to mult of 8) ----
__global__ void k_scan_a(const int* __restrict__ deg, int* __restrict__ bsum, int n) {
    __shared__ int sh[256];
    const int t = threadIdx.x, b = blockIdx.x;
    const int base = b * SCAN_CHUNK + t * 4;
    int s4 = 0;
#pragma unroll
    for (int q = 0; q < 4; ++q)
        if (base + q < n) s4 += (deg[base + q] + 7) & ~7;
    sh[t] = s4;
    __syncthreads();
    for (int o = 1; o < 256; o <<= 1) {
        int x = 0;
        if (t >= o) x = sh[t - o];
        __syncthreads();
        if (t >= o) sh[t] += x;
        __syncthreads();
    }
    if (t == 255) bsum[b] = sh[255];
}

// parallel scan of block sums (nblk <= 128)
__global__ void k_scan_b(int* __restrict__ bsum, int* __restrict__ rowptr, int nblk, int n) {
    __shared__ int sh[128];
    int t = threadIdx.x;
    int v = (t < nblk) ? bsum[t] : 0;
    sh[t] = v;
    __syncthreads();
    for (int o = 1; o < 128; o <<= 1) {
        int x = 0;
        if (t >= o) x = sh[t - o];
        __syncthreads();
        if (t >= o) sh[t] += x;
        __syncthreads();
    }
    if (t < nblk) bsum[t] = sh[t] - v;  // exclusive
    if (t == 127) rowptr[n] = sh[127];  // padded E
}

__global__ void k_scan_c(const int* __restrict__ deg, const int* __restrict__ bsum,
                         int* __restrict__ rowptr, int* __restrict__ pos, int n) {
    __shared__ int sh[256];
    const int t = threadIdx.x, b = blockIdx.x;
    const int base = b * SCAN_CHUNK + t * 4;
    int d[4];
    int s4 = 0;
#pragma unroll
    for (int q = 0; q < 4; ++q) {
        d[q] = (base + q < n) ? ((deg[base + q] + 7) & ~7) : 0;  // read BEFORE pos write
        s4 += d[q];
    }
    sh[t] = s4;
    __syncthreads();
    for (int o = 1; o < 256; o <<= 1) {
        int x = 0;
        if (t >= o) x = sh[t - o];
        __syncthreads();
        if (t >= o) sh[t] += x;
        __syncthreads();
    }
    int off = sh[t] - s4 + bsum[b];
#pragma unroll
    for (int q = 0; q < 4; ++q) {
        if (base + q < n) {
            rowptr[base + q] = off;
            pos[base + q] = off;
            off += d[q];
        }
    }
}

__global__ void k_fill(const int* __restrict__ src, const int* __restrict__ dst, int E,
                       int* __restrict__ pos, int* __restrict__ col) {
    int e = blockIdx.x * blockDim.x + threadIdx.x;
    if (e < E) {
        int p = atomicAdd(&pos[dst[e]], 1);
        col[p] = src[e];
    }
}

// fill padding slots with dummy node n (pos[i] == rowptr[i]+deg[i] after k_fill)
__global__ void k_pad(const int* __restrict__ rowptr, const int* __restrict__ pos,
                      int* __restrict__ col, int n) {
    int i = blockIdx.x * blockDim.x + threadIdx.x;
    if (i >= n) return;
    int p = pos[i], e = rowptr[i + 1];
    for (; p < e; ++p) col[p] = n;
}

// W1 [128][128] fp32 -> wt [nc][k] bf16 (transposed)
__global__ void k_transW(const float* __restrict__ W1, unsigned short* __restrict__ wt) {
    int i = blockIdx.x * 256 + threadIdx.x;  // 16384
    int nc = i >> 7, k = i & 127;
    wt[i] = f2bf(W1[k * 128 + nc]);
}

// ---- gemm1 (MFMA bf16): h' = dinv * (x @ W1). 64 rows/block, 4 waves ----
__global__ void k_gemm1(const float* __restrict__ x, const unsigned short* __restrict__ wt,
                        const float* __restrict__ dinv, unsigned short* __restrict__ h,
                        int n) {
    __shared__ unsigned short xs[64 * 136];  // 64 rows, stride 136 (16B-aligned, spread banks)
    const int t = threadIdx.x;
    const int row0 = blockIdx.x * 64;
    for (int i = t; i < 2048; i += 256) {  // 2048 float4 = 64x128 fp32 -> bf16
        int r = i >> 5, c4 = (i & 31) << 2;
        int gr = row0 + r;
        float4 v = make_float4(0.f, 0.f, 0.f, 0.f);
        if (gr < n) v = *(const float4*)(x + (size_t)gr * 128 + c4);
        ushort4 u;
        u.x = f2bf(v.x); u.y = f2bf(v.y); u.z = f2bf(v.z); u.w = f2bf(v.w);
        *(ushort4*)(xs + r * 136 + c4) = u;
    }
    __syncthreads();
    const int w = t >> 6;  // wave id: rows w*16 .. w*16+15
    const int lane = t & 63;
    const int m = lane & 15, q = lane >> 4;
    f32x4 acc[8];
#pragma unroll
    for (int ns = 0; ns < 8; ++ns) acc[ns] = (f32x4){0.f, 0.f, 0.f, 0.f};
#pragma unroll
    for (int kt = 0; kt < 4; ++kt) {
        short8 a = *(const short8*)(xs + (w * 16 + m) * 136 + kt * 32 + q * 8);
#pragma unroll
        for (int ns = 0; ns < 8; ++ns) {
            short8 b = *(const short8*)((const short*)wt + (ns * 16 + m) * 128 + kt * 32 + q * 8);
            acc[ns] = __builtin_amdgcn_mfma_f32_16x16x32_bf16(a, b, acc[ns], 0, 0, 0);
        }
    }
    // repack through this wave's own LDS slab (no cross-wave hazard), coalesced store
    unsigned short* xsw = xs + (w * 16) * 136;
    float srow[4];
#pragma unroll
    for (int reg = 0; reg < 4; ++reg) {
        int gr = row0 + w * 16 + q * 4 + reg;
        srow[reg] = (gr < n) ? dinv[gr] : 0.f;
    }
#pragma unroll
    for (int ns = 0; ns < 8; ++ns)
#pragma unroll
        for (int reg = 0; reg < 4; ++reg)
            xsw[(q * 4 + reg) * 136 + ns * 16 + m] = f2bf(acc[ns][reg] * srow[reg]);
    __syncthreads();  // also orders the wave's own LDS ops
#pragma unroll
    for (int it = 0; it < 8; ++it) {
        int rl = (lane >> 5) + it * 2;
        int off = (lane & 31) * 4;
        int gr = row0 + w * 16 + rl;
        if (gr < n)
            *(ushort4*)(h + (size_t)gr * 128 + off) = *(const ushort4*)(xsw + rl * 136 + off);
    }
}

// ---- fused gather1 + relu + (128->16 matvec) + scale. 32 lanes/node, unroll 8 ----
__global__ void k_gather1f(const unsigned short* __restrict__ h, const int* __restrict__ rowptr,
                           const int* __restrict__ col, const float* __restrict__ dinv,
                           const float* __restrict__ b1, const float* __restrict__ W2,
                           float* __restrict__ g, int n) {
    const int t = threadIdx.x;
    const int lane = t & 31;
    const int d = blockIdx.x * 8 + (t >> 5);
    if (d >= n) return;
    const float dd = dinv[d];

    float4 aA, aB, aC, aD;
    {   // self row
        ushort4 u = *(const ushort4*)(h + (size_t)d * 128 + lane * 4);
        aA.x = bf2f(u.x); aA.y = bf2f(u.y); aA.z = bf2f(u.z); aA.w = bf2f(u.w);
    }
    aB = make_float4(0.f, 0.f, 0.f, 0.f);
    aC = aB; aD = aB;
    int k = rowptr[d];
    const int end = rowptr[d + 1];
    for (; k < end; k += 8) {  // padded: always full batches of 8
        int4 c0 = *(const int4*)(col + k);
        int4 c1 = *(const int4*)(col + k + 4);
        ushort4 u0 = *(const ushort4*)(h + (size_t)c0.x * 128 + lane * 4);
        ushort4 u1 = *(const ushort4*)(h + (size_t)c0.y * 128 + lane * 4);
        ushort4 u2 = *(const ushort4*)(h + (size_t)c0.z * 128 + lane * 4);
        ushort4 u3 = *(const ushort4*)(h + (size_t)c0.w * 128 + lane * 4);
        ushort4 u4 = *(const ushort4*)(h + (size_t)c1.x * 128 + lane * 4);
        ushort4 u5 = *(const ushort4*)(h + (size_t)c1.y * 128 + lane * 4);
        ushort4 u6 = *(const ushort4*)(h + (size_t)c1.z * 128 + lane * 4);
        ushort4 u7 = *(const ushort4*)(h + (size_t)c1.w * 128 + lane * 4);
        aA.x += bf2f(u0.x); aA.y += bf2f(u0.y); aA.z += bf2f(u0.z); aA.w += bf2f(u0.w);
        aB.x += bf2f(u1.x); aB.y += bf2f(u1.y); aB.z += bf2f(u1.z); aB.w += bf2f(u1.w);
        aC.x += bf2f(u2.x); aC.y += bf2f(u2.y); aC.z += bf2f(u2.z); aC.w += bf2f(u2.w);
        aD.x += bf2f(u3.x); aD.y += bf2f(u3.y); aD.z += bf2f(u3.z); aD.w += bf2f(u3.w);
        aA.x += bf2f(u4.x); aA.y += bf2f(u4.y); aA.z += bf2f(u4.z); aA.w += bf2f(u4.w);
        aB.x += bf2f(u5.x); aB.y += bf2f(u5.y); aB.z += bf2f(u5.z); aB.w += bf2f(u5.w);
        aC.x += bf2f(u6.x); aC.y += bf2f(u6.y); aC.z += bf2f(u6.z); aC.w += bf2f(u6.w);
        aD.x += bf2f(u7.x); aD.y += bf2f(u7.y); aD.z += bf2f(u7.z); aD.w += bf2f(u7.w);
    }
    // y = relu(dd*sum + b1) — 4 features per lane
    const float4 b1v = *(const float4*)(b1 + lane * 4);
    float y0 = fmaxf(fmaf(aA.x + aB.x + aC.x + aD.x, dd, b1v.x), 0.f);
    float y1 = fmaxf(fmaf(aA.y + aB.y + aC.y + aD.y, dd, b1v.y), 0.f);
    float y2 = fmaxf(fmaf(aA.z + aB.z + aC.z + aD.z, dd, b1v.z), 0.f);
    float y3 = fmaxf(fmaf(aA.w + aB.w + aC.w + aD.w, dd, b1v.w), 0.f);
    // z[c] = sum_k y[k]*W2[k][c]; per-lane W2 rows 4*lane..4*lane+3
    const float4* w2v = (const float4*)(W2 + lane * 64);
    float4 z0 = make_float4(0.f, 0.f, 0.f, 0.f);
    float4 z1 = z0, z2 = z0, z3 = z0;
#pragma unroll
    for (int c4 = 0; c4 < 4; ++c4) {
        float4* z = (c4 == 0) ? &z0 : (c4 == 1) ? &z1 : (c4 == 2) ? &z2 : &z3;
        float4 w0 = w2v[0 * 4 + c4], w1 = w2v[1 * 4 + c4];
        float4 w2 = w2v[2 * 4 + c4], w3 = w2v[3 * 4 + c4];
        z->x = fmaf(y0, w0.x, fmaf(y1, w1.x, fmaf(y2, w2.x, fmaf(y3, w3.x, z->x))));
        z->y = fmaf(y0, w0.y, fmaf(y1, w1.y, fmaf(y2, w2.y, fmaf(y3, w3.y, z->y))));
        z->z = fmaf(y0, w0.z, fmaf(y1, w1.z, fmaf(y2, w2.z, fmaf(y3, w3.z, z->z))));
        z->w = fmaf(y0, w0.w, fmaf(y1, w1.w, fmaf(y2, w2.w, fmaf(y3, w3.w, z->w))));
    }
#pragma unroll
    for (int mm = 1; mm < 32; mm <<= 1) {
        z0.x += __shfl_xor(z0.x, mm); z0.y += __shfl_xor(z0.y, mm);
        z0.z += __shfl_xor(z0.z, mm); z0.w += __shfl_xor(z0.w, mm);
        z1.x += __shfl_xor(z1.x, mm); z1.y += __shfl_xor(z1.y, mm);
        z1.z += __shfl_xor(z1.z, mm); z1.w += __shfl_xor(z1.w, mm);
        z2.x += __shfl_xor(z2.x, mm); z2.y += __shfl_xor(z2.y, mm);
        z2.z += __shfl_xor(z2.z, mm); z2.w += __shfl_xor(z2.w, mm);
        z3.x += __shfl_xor(z3.x, mm); z3.y += __shfl_xor(z3.y, mm);
        z3.z += __shfl_xor(z3.z, mm); z3.w += __shfl_xor(z3.w, mm);
    }
    if (lane < 4) {
        float4 z = (lane == 0) ? z0 : (lane == 1) ? z1 : (lane == 2) ? z2 : z3;
        z.x *= dd; z.y *= dd; z.z *= dd; z.w *= dd;
        *(float4*)(g + (size_t)d * 16 + lane * 4) = z;
    }
}

// ---- gather2 + bias + log_softmax. 4 lanes/node, unroll 8 ----
__global__ void k_gather2(const float* __restrict__ g, const int* __restrict__ rowptr,
                          const int* __restrict__ col, const float* __restrict__ dinv,
                          const float* __restrict__ b2, float* __restrict__ out, int n) {
    const int t = threadIdx.x;
    const int d = blockIdx.x * 64 + (t >> 2);
    if (d >= n) return;
    const int l = t & 3;
    const float dd = dinv[d];
    float4 aA = *(const float4*)(g + (size_t)d * 16 + l * 4);  // self
    float4 aB = make_float4(0.f, 0.f, 0.f, 0.f);
    float4 aC = aB, aD = aB;
    int k = rowptr[d];
    const int end = rowptr[d + 1];
    for (; k < end; k += 8) {
        int4 c0 = *(const int4*)(col + k);
        int4 c1 = *(const int4*)(col + k + 4);
        float4 h0 = *(const float4*)(g + (size_t)c0.x * 16 + l * 4);
        float4 h1 = *(const float4*)(g + (size_t)c0.y * 16 + l * 4);
        float4 h2 = *(const float4*)(g + (size_t)c0.z * 16 + l * 4);
        float4 h3 = *(const float4*)(g + (size_t)c0.w * 16 + l * 4);
        float4 h4 = *(const float4*)(g + (size_t)c1.x * 16 + l * 4);
        float4 h5 = *(const float4*)(g + (size_t)c1.y * 16 + l * 4);
        float4 h6 = *(const float4*)(g + (size_t)c1.z * 16 + l * 4);
        float4 h7 = *(const float4*)(g + (size_t)c1.w * 16 + l * 4);
        aA.x += h0.x; aA.y += h0.y; aA.z += h0.z; aA.w += h0.w;
        aB.x += h1.x; aB.y += h1.y; aB.z += h1.z; aB.w += h1.w;
        aC.x += h2.x; aC.y += h2.y; aC.z += h2.z; aC.w += h2.w;
        aD.x += h3.x; aD.y += h3.y; aD.z += h3.z; aD.w += h3.w;
        aA.x += h4.x; aA.y += h4.y; aA.z += h4.z; aA.w += h4.w;
        aB.x += h5.x; aB.y += h5.y; aB.z += h5.z; aB.w += h5.w;
        aC.x += h6.x; aC.y += h6.y; aC.z += h6.z; aC.w += h6.w;
        aD.x += h7.x; aD.y += h7.y; aD.z += h7.z; aD.w += h7.w;
    }
    float4 bv = *(const float4*)(b2 + l * 4);
    float4 acc;
    acc.x = fmaf(aA.x + aB.x + aC.x + aD.x, dd, bv.x);
    acc.y = fmaf(aA.y + aB.y + aC.y + aD.y, dd, bv.y);
    acc.z = fmaf(aA.z + aB.z + aC.z + aD.z, dd, bv.z);
    acc.w = fmaf(aA.w + aB.w + aC.w + aD.w, dd, bv.w);
    *(float4*)(out + (size_t)d * 16 + l * 4) = acc;
    float m = fmaxf(fmaxf(acc.x, acc.y), fmaxf(acc.z, acc.w));
    m = fmaxf(m, __shfl_xor(m, 1));
    m = fmaxf(m, __shfl_xor(m, 2));
    float e = expf(acc.x - m) + expf(acc.y - m) + expf(acc.z - m) + expf(acc.w - m);
    e += __shfl_xor(e, 1);
    e += __shfl_xor(e, 2);
    float ls = m + logf(e);
    float4 o;
    o.x = acc.x - ls; o.y = acc.y - ls; o.z = acc.z - ls; o.w = acc.w - ls;
    *(float4*)(out + (size_t)n * 16 + (size_t)d * 16 + l * 4) = o;
}

static inline size_t align256(size_t v) { return (v + 255) & ~(size_t)255; }

extern "C" void kernel_launch(void* const* d_in, const int* in_sizes, int n_in,
                              void* d_out, int out_size, void* d_ws, size_t ws_size,
                              hipStream_t stream) {
    const float* x  = (const float*)d_in[0];
    const int*   ei = (const int*)d_in[1];
    const float* W1 = (const float*)d_in[2];
    const float* b1 = (const float*)d_in[3];
    const float* W2 = (const float*)d_in[4];
    const float* b2 = (const float*)d_in[5];
    float* out = (float*)d_out;

    const int n = in_sizes[0] / 128;  // 100000
    const int E = in_sizes[1] / 2;    // 1600000
    const int* src = ei;
    const int* dst = ei + E;
    const int NBLK = (n + SCAN_CHUNK - 1) / SCAN_CHUNK;  // 98 (<=128 required)

    // workspace layout, 256B-aligned (~45 MB)
    char* base = (char*)d_ws;
    size_t off = 0;
    int* deg = (int*)(base + off); off = align256(off + (size_t)n * 4);  // aliased with pos
    int* pos = deg;
    float* dinv = (float*)(base + off); off = align256(off + (size_t)n * 4);
    int* rowptr = (int*)(base + off); off = align256(off + ((size_t)n + 1) * 4);
    int* bsum = (int*)(base + off); off = align256(off + 4096);
    int* col = (int*)(base + off); off = align256(off + ((size_t)E + 8 * (size_t)n) * 4);
    unsigned short* wt = (unsigned short*)(base + off); off = align256(off + 128 * 128 * 2);
    unsigned short* h = (unsigned short*)(base + off); off = align256(off + ((size_t)n + 1) * 128 * 2);
    float* g = (float*)(base + off); off = align256(off + ((size_t)n + 1) * 16 * 4);

    // degree + dinv + padded CSR
    k_init<<<(n + 255) / 256, 256, 0, stream>>>(deg, h, g, n);
    k_count<<<(E + 255) / 256, 256, 0, stream>>>(dst, E, deg);
    k_dinv<<<(n + 255) / 256, 256, 0, stream>>>(deg, dinv, n);
    k_scan_a<<<NBLK, 256, 0, stream>>>(deg, bsum, n);
    k_scan_b<<<1, 128, 0, stream>>>(bsum, rowptr, NBLK, n);
    k_scan_c<<<NBLK, 256, 0, stream>>>(deg, bsum, rowptr, pos, n);
    k_fill<<<(E + 255) / 256, 256, 0, stream>>>(src, dst, E, pos, col);
    k_pad<<<(n + 255) / 256, 256, 0, stream>>>(rowptr, pos, col, n);

    // layer 1
    k_transW<<<64, 256, 0, stream>>>(W1, wt);
    k_gemm1<<<(n + 63) / 64, 256, 0, stream>>>(x, wt, dinv, h, n);
    k_gather1f<<<(n + 7) / 8, 256, 0, stream>>>(h, rowptr, col, dinv, b1, W2, g, n);

    // layer 2 aggregation (+ fused bias/softmax)
    k_gather2<<<(n + 63) / 64, 256, 0, stream>>>(g, rowptr, col, dinv, b2, out, n);
}